// Round 1
// baseline (874.565 us; speedup 1.0000x reference)
//
#include <hip/hip_runtime.h>
#include <stdint.h>

#define N_NODES 50000
#define NNZ     800000
#define SUP     3
#define D_IN    512
#define D_OUT   256

typedef __attribute__((ext_vector_type(8))) short bf16x8;
typedef __attribute__((ext_vector_type(4))) float f32x4;

static __device__ __forceinline__ unsigned short f2bf(float f) {
    unsigned int u = __float_as_uint(f);
    unsigned int r = (u + 0x7fffu + ((u >> 16) & 1u)) >> 16;
    return (unsigned short)r;
}
static __device__ __forceinline__ float bf2f(unsigned short h) {
    return __uint_as_float(((unsigned int)h) << 16);
}

// ---------------- W transpose + bf16 cast: W[s][k][n] -> Wt[s][n][k] ----------------
__global__ void wprep_kernel(const float* __restrict__ W, unsigned short* __restrict__ Wt) {
    int idx = blockIdx.x * 256 + threadIdx.x;      // over SUP*D_IN*D_OUT = 393216
    if (idx >= SUP * D_IN * D_OUT) return;
    int n = idx & (D_OUT - 1);
    int k = (idx >> 8) & (D_IN - 1);
    int s = idx >> 17;
    Wt[((size_t)s * D_OUT + n) * D_IN + k] = f2bf(W[idx]);
}

// ---------------- histogram of rows ----------------
__global__ void hist_kernel(const int* __restrict__ rows, int* __restrict__ cnt) {
    int s = blockIdx.y;
    int n = blockIdx.x * 256 + threadIdx.x;
    if (n >= NNZ) return;
    atomicAdd(&cnt[s * N_NODES + rows[(size_t)s * NNZ + n]], 1);
}

// ---------------- exclusive scan per support (1 block/support) ----------------
__global__ __launch_bounds__(1024) void scan_kernel(int* __restrict__ cnt_cursor,
                                                    int* __restrict__ row_start) {
    __shared__ int sm[1024];
    __shared__ int carry_sh;
    int s = blockIdx.x;
    int* c  = cnt_cursor + s * N_NODES;
    int* rs = row_start + s * (N_NODES + 1);
    if (threadIdx.x == 0) carry_sh = 0;
    __syncthreads();
    for (int base = 0; base < N_NODES; base += 1024) {
        int i = base + threadIdx.x;
        int v = (i < N_NODES) ? c[i] : 0;
        sm[threadIdx.x] = v;
        __syncthreads();
        for (int off = 1; off < 1024; off <<= 1) {
            int t = (threadIdx.x >= off) ? sm[threadIdx.x - off] : 0;
            __syncthreads();
            sm[threadIdx.x] += t;
            __syncthreads();
        }
        int carry = carry_sh;
        int excl  = carry + sm[threadIdx.x] - v;
        int total = sm[1023];
        if (i < N_NODES) { rs[i] = excl; c[i] = excl; }
        __syncthreads();
        if (threadIdx.x == 0) carry_sh = carry + total;
        __syncthreads();
    }
    if (threadIdx.x == 0) rs[N_NODES] = carry_sh;
}

// ---------------- scatter into CSR order ----------------
__global__ void scatter_kernel(const int* __restrict__ rows, const int* __restrict__ cols,
                               const float* __restrict__ vals, int* __restrict__ cursor,
                               int2* __restrict__ cv) {
    int s = blockIdx.y;
    int n = blockIdx.x * 256 + threadIdx.x;
    if (n >= NNZ) return;
    int r   = rows[(size_t)s * NNZ + n];
    int c   = cols[(size_t)s * NNZ + n];
    float v = vals[(size_t)s * NNZ + n];
    int pos = atomicAdd(&cursor[s * N_NODES + r], 1);
    cv[(size_t)s * NNZ + pos] = make_int2(c, __float_as_int(v));
}

// ---------------- bf16 MFMA GEMM: pre[s] = x @ W[s], stored bf16 ----------------
// 128x128 tile, 4 waves, each wave 64x64 via 4x4 grid of 16x16x32 MFMAs.
__global__ __launch_bounds__(256) void gemm_kernel(const float* __restrict__ x,
                                                   const unsigned short* __restrict__ Wt,
                                                   unsigned short* __restrict__ pre) {
    __shared__ unsigned short lds_a[128 * 40];   // [m][k], rows padded to 40 elems (80B)
    __shared__ unsigned short lds_b[128 * 40];   // [n][k]
    const int m0 = blockIdx.x * 128;
    const int n0 = blockIdx.y * 128;
    const int s  = blockIdx.z;
    const unsigned short* wt = Wt + (size_t)s * D_OUT * D_IN;   // [256][512]
    const int tid  = threadIdx.x;
    const int wave = tid >> 6;
    const int lane = tid & 63;
    const int quad = lane >> 4;
    const int lo   = lane & 15;
    const int wm = (wave & 1) * 64;
    const int wn = (wave >> 1) * 64;

    f32x4 acc[4][4] = {};

    const int ar = tid >> 1;              // 0..127: row within tile
    const int ac = (tid & 1) * 16;        // k-offset 0 or 16
    const int gm = m0 + ar;
    const float* xrow = x + (size_t)gm * D_IN;
    const unsigned short* wrow = wt + (size_t)(n0 + ar) * D_IN;

    for (int kb = 0; kb < D_IN; kb += 32) {
        // global loads into regs
        unsigned int aw[8];
        if (gm < N_NODES) {
            #pragma unroll
            for (int q = 0; q < 4; ++q) {
                float4 f = *(const float4*)(xrow + kb + ac + q * 4);
                aw[2*q]   = (unsigned int)f2bf(f.x) | ((unsigned int)f2bf(f.y) << 16);
                aw[2*q+1] = (unsigned int)f2bf(f.z) | ((unsigned int)f2bf(f.w) << 16);
            }
        } else {
            #pragma unroll
            for (int q = 0; q < 8; ++q) aw[q] = 0;
        }
        uint4 b0 = *(const uint4*)(wrow + kb + ac);
        uint4 b1 = *(const uint4*)(wrow + kb + ac + 8);

        __syncthreads();   // previous iteration's LDS reads done
        *(uint4*)&lds_a[ar * 40 + ac]     = make_uint4(aw[0], aw[1], aw[2], aw[3]);
        *(uint4*)&lds_a[ar * 40 + ac + 8] = make_uint4(aw[4], aw[5], aw[6], aw[7]);
        *(uint4*)&lds_b[ar * 40 + ac]     = b0;
        *(uint4*)&lds_b[ar * 40 + ac + 8] = b1;
        __syncthreads();

        bf16x8 af[4], bfr[4];
        #pragma unroll
        for (int i = 0; i < 4; ++i)
            af[i] = *(const bf16x8*)&lds_a[(wm + 16 * i + lo) * 40 + quad * 8];
        #pragma unroll
        for (int j = 0; j < 4; ++j)
            bfr[j] = *(const bf16x8*)&lds_b[(wn + 16 * j + lo) * 40 + quad * 8];
        #pragma unroll
        for (int i = 0; i < 4; ++i)
            #pragma unroll
            for (int j = 0; j < 4; ++j)
                acc[i][j] = __builtin_amdgcn_mfma_f32_16x16x32_bf16(af[i], bfr[j], acc[i][j], 0, 0, 0);
    }

    // epilogue: C layout col=lane&15, row=quad*4+reg
    #pragma unroll
    for (int i = 0; i < 4; ++i) {
        #pragma unroll
        for (int j = 0; j < 4; ++j) {
            int gn = n0 + wn + 16 * j + lo;
            #pragma unroll
            for (int r = 0; r < 4; ++r) {
                int gm2 = m0 + wm + 16 * i + quad * 4 + r;
                if (gm2 < N_NODES)
                    pre[((size_t)s * N_NODES + gm2) * D_OUT + gn] = f2bf(acc[i][j][r]);
            }
        }
    }
}

// ---------------- fused SpMM over 3 supports + cw-weighted sum + ReLU ----------------
// one wave per output row; lane owns 4 contiguous output columns
__global__ __launch_bounds__(256) void spmm_kernel(const unsigned short* __restrict__ pre,
                                                   const int* __restrict__ row_start,
                                                   const int2* __restrict__ cv,
                                                   const float* __restrict__ cw,
                                                   float* __restrict__ out) {
    int row  = blockIdx.x * 4 + (threadIdx.x >> 6);
    int lane = threadIdx.x & 63;
    float a0 = 0.f, a1 = 0.f, a2 = 0.f, a3 = 0.f;
    #pragma unroll
    for (int s = 0; s < SUP; ++s) {
        float cws = cw[s];
        const int* rs = row_start + s * (N_NODES + 1);
        int start = rs[row], end = rs[row + 1];
        const int2* cvp = cv + (size_t)s * NNZ;
        const unsigned short* ps = pre + (size_t)s * N_NODES * D_OUT;
        for (int j = start; j < end; ++j) {
            int2 e  = cvp[j];
            float w = cws * __int_as_float(e.y);
            ushort4 p = *(const ushort4*)(ps + (size_t)e.x * D_OUT + lane * 4);
            a0 += w * bf2f(p.x);
            a1 += w * bf2f(p.y);
            a2 += w * bf2f(p.z);
            a3 += w * bf2f(p.w);
        }
    }
    float4 o = make_float4(fmaxf(a0, 0.f), fmaxf(a1, 0.f), fmaxf(a2, 0.f), fmaxf(a3, 0.f));
    *(float4*)(out + (size_t)row * D_OUT + lane * 4) = o;
}

extern "C" void kernel_launch(void* const* d_in, const int* in_sizes, int n_in,
                              void* d_out, int out_size, void* d_ws, size_t ws_size,
                              hipStream_t stream) {
    const float* x    = (const float*)d_in[0];
    const float* W    = (const float*)d_in[1];
    const int*   rows = (const int*)d_in[2];
    const int*   cols = (const int*)d_in[3];
    const float* vals = (const float*)d_in[4];
    const float* cw   = (const float*)d_in[5];
    float* out = (float*)d_out;

    char* ws = (char*)d_ws;
    size_t off = 0;
    auto alloc = [&](size_t bytes) -> void* {
        void* p = ws + off;
        off += (bytes + 255) & ~(size_t)255;
        return p;
    };
    unsigned short* pre  = (unsigned short*)alloc((size_t)SUP * N_NODES * D_OUT * 2); // 76.8 MB
    unsigned short* Wt   = (unsigned short*)alloc((size_t)SUP * D_OUT * D_IN * 2);    // 0.8 MB
    int* row_start       = (int*)alloc((size_t)SUP * (N_NODES + 1) * 4);              // 0.6 MB
    int* cursor          = (int*)alloc((size_t)SUP * N_NODES * 4);                    // 0.6 MB
    int2* cv             = (int2*)alloc((size_t)SUP * NNZ * 8);                       // 19.2 MB

    hipMemsetAsync(cursor, 0, (size_t)SUP * N_NODES * 4, stream);

    hist_kernel<<<dim3((NNZ + 255) / 256, SUP), 256, 0, stream>>>(rows, cursor);
    scan_kernel<<<SUP, 1024, 0, stream>>>(cursor, row_start);
    scatter_kernel<<<dim3((NNZ + 255) / 256, SUP), 256, 0, stream>>>(rows, cols, vals, cursor, cv);
    wprep_kernel<<<(SUP * D_IN * D_OUT + 255) / 256, 256, 0, stream>>>(W, Wt);
    gemm_kernel<<<dim3((N_NODES + 127) / 128, D_OUT / 128, SUP), 256, 0, stream>>>(x, Wt, pre);
    spmm_kernel<<<N_NODES / 4, 256, 0, stream>>>(pre, row_start, cv, cw, out);
}

// Round 2
// 737.590 us; speedup vs baseline: 1.1857x; 1.1857x over previous
//
#include <hip/hip_runtime.h>
#include <stdint.h>

#define N_NODES 50000
#define NNZ     800000
#define SUP     3
#define D_IN    512
#define D_OUT   256

typedef __attribute__((ext_vector_type(8))) short bf16x8;
typedef __attribute__((ext_vector_type(4))) float f32x4;

static __device__ __forceinline__ unsigned short f2bf(float f) {
    unsigned int u = __float_as_uint(f);
    unsigned int r = (u + 0x7fffu + ((u >> 16) & 1u)) >> 16;
    return (unsigned short)r;
}
// round-half-up pack of two floats into bf16 pair (cheap: 2 add, 1 shift, 1 and, 1 or)
static __device__ __forceinline__ unsigned int pack_bf2(float lo, float hi) {
    unsigned int a = __float_as_uint(lo) + 0x8000u;
    unsigned int b = __float_as_uint(hi) + 0x8000u;
    return (a >> 16) | (b & 0xffff0000u);
}
static __device__ __forceinline__ float bf2f(unsigned short h) {
    return __uint_as_float(((unsigned int)h) << 16);
}

// ---------------- W transpose + bf16 cast: W[s][k][n] -> Wt[s][n][k] ----------------
__global__ void wprep_kernel(const float* __restrict__ W, unsigned short* __restrict__ Wt) {
    int idx = blockIdx.x * 256 + threadIdx.x;      // over SUP*D_IN*D_OUT = 393216
    if (idx >= SUP * D_IN * D_OUT) return;
    int n = idx & (D_OUT - 1);
    int k = (idx >> 8) & (D_IN - 1);
    int s = idx >> 17;
    Wt[((size_t)s * D_OUT + n) * D_IN + k] = f2bf(W[idx]);
}

// ---------------- combined histogram of rows (all supports into one count) ----------
__global__ void hist_kernel(const int* __restrict__ rows, int* __restrict__ cnt) {
    int s = blockIdx.y;
    int n = blockIdx.x * 256 + threadIdx.x;
    if (n >= NNZ) return;
    atomicAdd(&cnt[rows[(size_t)s * NNZ + n]], 1);
}

// ---------------- scan-free row allocation: wave prefix + one atomic per wave ------
__global__ void rowalloc_kernel(const int* __restrict__ cnt, int* __restrict__ base,
                                int* __restrict__ cursor, int* __restrict__ gcount) {
    int i = blockIdx.x * 256 + threadIdx.x;
    int lane = threadIdx.x & 63;
    int v = (i < N_NODES) ? cnt[i] : 0;
    int p = v;
    #pragma unroll
    for (int off = 1; off < 64; off <<= 1) {
        int t = __shfl_up(p, off, 64);
        if (lane >= off) p += t;
    }
    int total = __shfl(p, 63, 64);
    int wb = 0;
    if (lane == 0) wb = atomicAdd(gcount, total);
    wb = __shfl(wb, 0, 64);
    int b = wb + p - v;
    if (i < N_NODES) { base[i] = b; cursor[i] = b; }
}

// ---------------- scatter into combined CSR, folding cw[s] into the value ----------
__global__ void scatter_kernel(const int* __restrict__ rows, const int* __restrict__ cols,
                               const float* __restrict__ vals, const float* __restrict__ cw,
                               int* __restrict__ cursor, int2* __restrict__ cv) {
    int s = blockIdx.y;
    int n = blockIdx.x * 256 + threadIdx.x;
    if (n >= NNZ) return;
    int r   = rows[(size_t)s * NNZ + n];
    int c   = cols[(size_t)s * NNZ + n];
    float v = vals[(size_t)s * NNZ + n] * cw[s];
    int pos = atomicAdd(&cursor[r], 1);
    cv[pos] = make_int2(s * N_NODES + c, __float_as_int(v));
}

// ---------------- bf16 MFMA GEMM: pre[s] = x @ W[s], stored bf16 -------------------
__global__ __launch_bounds__(256) void gemm_kernel(const float* __restrict__ x,
                                                   const unsigned short* __restrict__ Wt,
                                                   unsigned short* __restrict__ pre) {
    __shared__ unsigned short lds_a[128 * 40];   // [m][k], rows padded to 40 elems
    __shared__ unsigned short lds_b[128 * 40];   // [n][k]
    const int m0 = blockIdx.x * 128;
    const int n0 = blockIdx.y * 128;
    const int s  = blockIdx.z;
    const unsigned short* wt = Wt + (size_t)s * D_OUT * D_IN;
    const int tid  = threadIdx.x;
    const int wave = tid >> 6;
    const int lane = tid & 63;
    const int quad = lane >> 4;
    const int lo   = lane & 15;
    const int wm = (wave & 1) * 64;
    const int wn = (wave >> 1) * 64;

    f32x4 acc[4][4] = {};

    const int ar = tid >> 1;              // 0..127: row within tile
    const int ac = (tid & 1) * 16;        // k-offset 0 or 16
    const int gm = m0 + ar;
    const float* xrow = x + (size_t)gm * D_IN;
    const unsigned short* wrow = wt + (size_t)(n0 + ar) * D_IN;

    for (int kb = 0; kb < D_IN; kb += 32) {
        unsigned int aw[8];
        if (gm < N_NODES) {
            float4 f0 = *(const float4*)(xrow + kb + ac);
            float4 f1 = *(const float4*)(xrow + kb + ac + 4);
            float4 f2 = *(const float4*)(xrow + kb + ac + 8);
            float4 f3 = *(const float4*)(xrow + kb + ac + 12);
            aw[0] = pack_bf2(f0.x, f0.y); aw[1] = pack_bf2(f0.z, f0.w);
            aw[2] = pack_bf2(f1.x, f1.y); aw[3] = pack_bf2(f1.z, f1.w);
            aw[4] = pack_bf2(f2.x, f2.y); aw[5] = pack_bf2(f2.z, f2.w);
            aw[6] = pack_bf2(f3.x, f3.y); aw[7] = pack_bf2(f3.z, f3.w);
        } else {
            #pragma unroll
            for (int q = 0; q < 8; ++q) aw[q] = 0;
        }
        uint4 b0 = *(const uint4*)(wrow + kb + ac);
        uint4 b1 = *(const uint4*)(wrow + kb + ac + 8);

        __syncthreads();
        *(uint4*)&lds_a[ar * 40 + ac]     = make_uint4(aw[0], aw[1], aw[2], aw[3]);
        *(uint4*)&lds_a[ar * 40 + ac + 8] = make_uint4(aw[4], aw[5], aw[6], aw[7]);
        *(uint4*)&lds_b[ar * 40 + ac]     = b0;
        *(uint4*)&lds_b[ar * 40 + ac + 8] = b1;
        __syncthreads();

        bf16x8 af[4], bfr[4];
        #pragma unroll
        for (int i = 0; i < 4; ++i)
            af[i] = *(const bf16x8*)&lds_a[(wm + 16 * i + lo) * 40 + quad * 8];
        #pragma unroll
        for (int j = 0; j < 4; ++j)
            bfr[j] = *(const bf16x8*)&lds_b[(wn + 16 * j + lo) * 40 + quad * 8];
        #pragma unroll
        for (int i = 0; i < 4; ++i)
            #pragma unroll
            for (int j = 0; j < 4; ++j)
                acc[i][j] = __builtin_amdgcn_mfma_f32_16x16x32_bf16(af[i], bfr[j], acc[i][j], 0, 0, 0);
    }

    #pragma unroll
    for (int i = 0; i < 4; ++i) {
        #pragma unroll
        for (int j = 0; j < 4; ++j) {
            int gn = n0 + wn + 16 * j + lo;
            #pragma unroll
            for (int r = 0; r < 4; ++r) {
                int gm2 = m0 + wm + 16 * i + quad * 4 + r;
                if (gm2 < N_NODES)
                    pre[((size_t)s * N_NODES + gm2) * D_OUT + gn] = f2bf(acc[i][j][r]);
            }
        }
    }
}

// ---------------- fused SpMM (combined CSR) + ReLU, unroll x4 for MLP --------------
__global__ __launch_bounds__(256) void spmm_kernel(const unsigned short* __restrict__ pre,
                                                   const int* __restrict__ base,
                                                   const int* __restrict__ cnt,
                                                   const int2* __restrict__ cv,
                                                   float* __restrict__ out) {
    int row  = blockIdx.x * 4 + (threadIdx.x >> 6);
    int lane = threadIdx.x & 63;
    int start = base[row];
    int end   = start + cnt[row];
    float a0 = 0.f, a1 = 0.f, a2 = 0.f, a3 = 0.f;
    int j = start;
    for (; j + 4 <= end; j += 4) {
        int2 e0 = cv[j + 0];
        int2 e1 = cv[j + 1];
        int2 e2 = cv[j + 2];
        int2 e3 = cv[j + 3];
        ushort4 p0 = *(const ushort4*)(pre + (size_t)e0.x * D_OUT + lane * 4);
        ushort4 p1 = *(const ushort4*)(pre + (size_t)e1.x * D_OUT + lane * 4);
        ushort4 p2 = *(const ushort4*)(pre + (size_t)e2.x * D_OUT + lane * 4);
        ushort4 p3 = *(const ushort4*)(pre + (size_t)e3.x * D_OUT + lane * 4);
        float w0 = __int_as_float(e0.y), w1 = __int_as_float(e1.y);
        float w2 = __int_as_float(e2.y), w3 = __int_as_float(e3.y);
        a0 += w0 * bf2f(p0.x) + w1 * bf2f(p1.x) + w2 * bf2f(p2.x) + w3 * bf2f(p3.x);
        a1 += w0 * bf2f(p0.y) + w1 * bf2f(p1.y) + w2 * bf2f(p2.y) + w3 * bf2f(p3.y);
        a2 += w0 * bf2f(p0.z) + w1 * bf2f(p1.z) + w2 * bf2f(p2.z) + w3 * bf2f(p3.z);
        a3 += w0 * bf2f(p0.w) + w1 * bf2f(p1.w) + w2 * bf2f(p2.w) + w3 * bf2f(p3.w);
    }
    for (; j < end; ++j) {
        int2 e = cv[j];
        float w = __int_as_float(e.y);
        ushort4 p = *(const ushort4*)(pre + (size_t)e.x * D_OUT + lane * 4);
        a0 += w * bf2f(p.x);
        a1 += w * bf2f(p.y);
        a2 += w * bf2f(p.z);
        a3 += w * bf2f(p.w);
    }
    float4 o = make_float4(fmaxf(a0, 0.f), fmaxf(a1, 0.f), fmaxf(a2, 0.f), fmaxf(a3, 0.f));
    *(float4*)(out + (size_t)row * D_OUT + lane * 4) = o;
}

extern "C" void kernel_launch(void* const* d_in, const int* in_sizes, int n_in,
                              void* d_out, int out_size, void* d_ws, size_t ws_size,
                              hipStream_t stream) {
    const float* x    = (const float*)d_in[0];
    const float* W    = (const float*)d_in[1];
    const int*   rows = (const int*)d_in[2];
    const int*   cols = (const int*)d_in[3];
    const float* vals = (const float*)d_in[4];
    const float* cw   = (const float*)d_in[5];
    float* out = (float*)d_out;

    char* ws = (char*)d_ws;
    size_t off = 0;
    auto alloc = [&](size_t bytes) -> void* {
        void* p = ws + off;
        off += (bytes + 255) & ~(size_t)255;
        return p;
    };
    unsigned short* pre  = (unsigned short*)alloc((size_t)SUP * N_NODES * D_OUT * 2); // 76.8 MB
    unsigned short* Wt   = (unsigned short*)alloc((size_t)SUP * D_OUT * D_IN * 2);    // 0.8 MB
    int* base            = (int*)alloc((size_t)N_NODES * 4);                          // 0.2 MB
    int* cnt             = (int*)alloc((size_t)N_NODES * 4);                          // 0.2 MB
    int* cursor          = (int*)alloc((size_t)N_NODES * 4);                          // 0.2 MB
    int* gcount          = (int*)alloc(256);
    int2* cv             = (int2*)alloc((size_t)SUP * NNZ * 8);                       // 19.2 MB

    hipMemsetAsync(cnt, 0, (size_t)N_NODES * 4, stream);
    hipMemsetAsync(gcount, 0, 4, stream);

    hist_kernel<<<dim3((NNZ + 255) / 256, SUP), 256, 0, stream>>>(rows, cnt);
    rowalloc_kernel<<<(N_NODES + 255) / 256, 256, 0, stream>>>(cnt, base, cursor, gcount);
    scatter_kernel<<<dim3((NNZ + 255) / 256, SUP), 256, 0, stream>>>(rows, cols, vals, cw, cursor, cv);
    wprep_kernel<<<(SUP * D_IN * D_OUT + 255) / 256, 256, 0, stream>>>(W, Wt);
    gemm_kernel<<<dim3((N_NODES + 127) / 128, D_OUT / 128, SUP), 256, 0, stream>>>(x, Wt, pre);
    spmm_kernel<<<N_NODES / 4, 256, 0, stream>>>(pre, base, cnt, cv, out);
}

// Round 3
// 516.272 us; speedup vs baseline: 1.6940x; 1.4287x over previous
//
#include <hip/hip_runtime.h>
#include <stdint.h>

#define N_NODES 50000
#define NNZ     800000
#define SUP     3
#define D_IN    512
#define D_OUT   256
#define TOT_E   (SUP * NNZ)          // 2,400,000
#define NBUCK   196                  // ceil(50000/256)
#define CAP     13312                // per-bucket capacity (mean 12245, +8 sigma)
#define CHUNK   10240                // edges per pass-1 block

typedef __attribute__((ext_vector_type(8))) short bf16x8;
typedef __attribute__((ext_vector_type(4))) float f32x4;

static __device__ __forceinline__ unsigned short f2bf(float f) {
    unsigned int u = __float_as_uint(f);
    unsigned int r = (u + 0x7fffu + ((u >> 16) & 1u)) >> 16;
    return (unsigned short)r;
}
static __device__ __forceinline__ unsigned int pack_bf2(float lo, float hi) {
    unsigned int a = __float_as_uint(lo) + 0x8000u;
    unsigned int b = __float_as_uint(hi) + 0x8000u;
    return (a >> 16) | (b & 0xffff0000u);
}
static __device__ __forceinline__ float bf2f(unsigned short h) {
    return __uint_as_float(((unsigned int)h) << 16);
}

// ---------------- W transpose + bf16 cast: W[s][k][n] -> Wt[s][n][k] ----------------
__global__ void wprep_kernel(const float* __restrict__ W, unsigned short* __restrict__ Wt) {
    int idx = blockIdx.x * 256 + threadIdx.x;
    if (idx >= SUP * D_IN * D_OUT) return;
    int n = idx & (D_OUT - 1);
    int k = (idx >> 8) & (D_IN - 1);
    int s = idx >> 17;
    Wt[((size_t)s * D_OUT + n) * D_IN + k] = f2bf(W[idx]);
}

// ---------------- pass 1: bucket edges by row>>8, coalesced run writes --------------
__global__ __launch_bounds__(256) void bucket_kernel(const int* __restrict__ rows,
                                                     const int* __restrict__ cols,
                                                     const float* __restrict__ vals,
                                                     const float* __restrict__ cw,
                                                     int* __restrict__ bucket_cursor,
                                                     int2* __restrict__ buck) {
    __shared__ int hist[NBUCK];
    __shared__ int sc[256];          // scan workspace
    __shared__ int sstart[NBUCK];    // exclusive start per bucket (local)
    __shared__ int lcur[NBUCK];      // local cursor
    __shared__ int gbase[NBUCK];     // global base within bucket region
    __shared__ unsigned char bucket_of[CHUNK];
    __shared__ int2 stage[CHUNK];    // 80 KB

    const int tid = threadIdx.x;
    const int base_n = blockIdx.x * CHUNK;
    const int count = min(CHUNK, TOT_E - base_n);
    float cw0 = cw[0], cw1 = cw[1], cw2 = cw[2];

    for (int i = tid; i < NBUCK; i += 256) hist[i] = 0;
    __syncthreads();
    for (int i = tid; i < count; i += 256) {
        atomicAdd(&hist[rows[base_n + i] >> 8], 1);
    }
    __syncthreads();
    // inclusive scan over 256 (padded)
    sc[tid] = (tid < NBUCK) ? hist[tid] : 0;
    __syncthreads();
    for (int off = 1; off < 256; off <<= 1) {
        int t = (tid >= off) ? sc[tid - off] : 0;
        __syncthreads();
        sc[tid] += t;
        __syncthreads();
    }
    if (tid < NBUCK) {
        int st = sc[tid] - hist[tid];
        sstart[tid] = st;
        lcur[tid]   = st;
        gbase[tid]  = atomicAdd(&bucket_cursor[tid], hist[tid]);
    }
    __syncthreads();
    // place into LDS staging, grouped by bucket
    for (int i = tid; i < count; i += 256) {
        int n = base_n + i;
        int r = rows[n];
        int c = cols[n];
        float v = vals[n];
        int s = n / NNZ;
        float w = v * (s == 0 ? cw0 : (s == 1 ? cw1 : cw2));
        int b = r >> 8;
        int p = atomicAdd(&lcur[b], 1);
        stage[p] = make_int2(((r & 255) << 18) | (s * N_NODES + c), __float_as_int(w));
        bucket_of[p] = (unsigned char)b;
    }
    __syncthreads();
    // write out: contiguous runs per bucket
    for (int i = tid; i < count; i += 256) {
        int b = bucket_of[i];
        int local_off = i - sstart[b];
        buck[(size_t)b * CAP + gbase[b] + local_off] = stage[i];
    }
}

// ---------------- pass 2: sort each bucket by row via LDS, emit CSR + base/cnt -----
__global__ __launch_bounds__(256) void sort_kernel(const int2* __restrict__ buck,
                                                   const int* __restrict__ bucket_cursor,
                                                   int2* __restrict__ cv,
                                                   int* __restrict__ base,
                                                   int* __restrict__ cnt) {
    __shared__ int hist[256];
    __shared__ int sc[256];
    __shared__ int sstart[256];
    __shared__ int cur[256];
    __shared__ int2 stage[CAP];      // 104 KB

    const int b = blockIdx.x;
    const int tid = threadIdx.x;
    const int sz = bucket_cursor[b];
    const int2* src = buck + (size_t)b * CAP;

    hist[tid] = 0;
    __syncthreads();
    for (int i = tid; i < sz; i += 256) {
        atomicAdd(&hist[((unsigned)src[i].x) >> 18], 1);
    }
    __syncthreads();
    sc[tid] = hist[tid];
    __syncthreads();
    for (int off = 1; off < 256; off <<= 1) {
        int t = (tid >= off) ? sc[tid - off] : 0;
        __syncthreads();
        sc[tid] += t;
        __syncthreads();
    }
    int st = sc[tid] - hist[tid];
    sstart[tid] = st;
    cur[tid] = st;
    __syncthreads();
    for (int i = tid; i < sz; i += 256) {
        int2 e = src[i];
        int rl = ((unsigned)e.x) >> 18;
        int p = atomicAdd(&cur[rl], 1);
        stage[p] = make_int2(e.x & 0x3FFFF, e.y);
    }
    __syncthreads();
    size_t gb = (size_t)b * CAP;
    for (int i = tid; i < sz; i += 256) cv[gb + i] = stage[i];
    int r = b * 256 + tid;
    if (r < N_NODES) {
        base[r] = (int)gb + sstart[tid];
        cnt[r]  = hist[tid];
    }
}

// ---------------- bf16 MFMA GEMM: pre[s] = x @ W[s], stored bf16 -------------------
__global__ __launch_bounds__(256) void gemm_kernel(const float* __restrict__ x,
                                                   const unsigned short* __restrict__ Wt,
                                                   unsigned short* __restrict__ pre) {
    __shared__ unsigned short lds_a[128 * 40];
    __shared__ unsigned short lds_b[128 * 40];
    const int m0 = blockIdx.x * 128;
    const int n0 = blockIdx.y * 128;
    const int s  = blockIdx.z;
    const unsigned short* wt = Wt + (size_t)s * D_OUT * D_IN;
    const int tid  = threadIdx.x;
    const int wave = tid >> 6;
    const int lane = tid & 63;
    const int quad = lane >> 4;
    const int lo   = lane & 15;
    const int wm = (wave & 1) * 64;
    const int wn = (wave >> 1) * 64;

    f32x4 acc[4][4] = {};

    const int ar = tid >> 1;
    const int ac = (tid & 1) * 16;
    const int gm = m0 + ar;
    const float* xrow = x + (size_t)gm * D_IN;
    const unsigned short* wrow = wt + (size_t)(n0 + ar) * D_IN;

    for (int kb = 0; kb < D_IN; kb += 32) {
        unsigned int aw[8];
        if (gm < N_NODES) {
            float4 f0 = *(const float4*)(xrow + kb + ac);
            float4 f1 = *(const float4*)(xrow + kb + ac + 4);
            float4 f2 = *(const float4*)(xrow + kb + ac + 8);
            float4 f3 = *(const float4*)(xrow + kb + ac + 12);
            aw[0] = pack_bf2(f0.x, f0.y); aw[1] = pack_bf2(f0.z, f0.w);
            aw[2] = pack_bf2(f1.x, f1.y); aw[3] = pack_bf2(f1.z, f1.w);
            aw[4] = pack_bf2(f2.x, f2.y); aw[5] = pack_bf2(f2.z, f2.w);
            aw[6] = pack_bf2(f3.x, f3.y); aw[7] = pack_bf2(f3.z, f3.w);
        } else {
            #pragma unroll
            for (int q = 0; q < 8; ++q) aw[q] = 0;
        }
        uint4 b0 = *(const uint4*)(wrow + kb + ac);
        uint4 b1 = *(const uint4*)(wrow + kb + ac + 8);

        __syncthreads();
        *(uint4*)&lds_a[ar * 40 + ac]     = make_uint4(aw[0], aw[1], aw[2], aw[3]);
        *(uint4*)&lds_a[ar * 40 + ac + 8] = make_uint4(aw[4], aw[5], aw[6], aw[7]);
        *(uint4*)&lds_b[ar * 40 + ac]     = b0;
        *(uint4*)&lds_b[ar * 40 + ac + 8] = b1;
        __syncthreads();

        bf16x8 af[4], bfr[4];
        #pragma unroll
        for (int i = 0; i < 4; ++i)
            af[i] = *(const bf16x8*)&lds_a[(wm + 16 * i + lo) * 40 + quad * 8];
        #pragma unroll
        for (int j = 0; j < 4; ++j)
            bfr[j] = *(const bf16x8*)&lds_b[(wn + 16 * j + lo) * 40 + quad * 8];
        #pragma unroll
        for (int i = 0; i < 4; ++i)
            #pragma unroll
            for (int j = 0; j < 4; ++j)
                acc[i][j] = __builtin_amdgcn_mfma_f32_16x16x32_bf16(af[i], bfr[j], acc[i][j], 0, 0, 0);
    }

    #pragma unroll
    for (int i = 0; i < 4; ++i) {
        #pragma unroll
        for (int j = 0; j < 4; ++j) {
            int gn = n0 + wn + 16 * j + lo;
            #pragma unroll
            for (int r = 0; r < 4; ++r) {
                int gm2 = m0 + wm + 16 * i + quad * 4 + r;
                if (gm2 < N_NODES)
                    pre[((size_t)s * N_NODES + gm2) * D_OUT + gn] = f2bf(acc[i][j][r]);
            }
        }
    }
}

// ---------------- fused SpMM (combined CSR) + ReLU, unroll x4 ----------------------
__global__ __launch_bounds__(256) void spmm_kernel(const unsigned short* __restrict__ pre,
                                                   const int* __restrict__ base,
                                                   const int* __restrict__ cnt,
                                                   const int2* __restrict__ cv,
                                                   float* __restrict__ out) {
    int row  = blockIdx.x * 4 + (threadIdx.x >> 6);
    int lane = threadIdx.x & 63;
    int start = base[row];
    int end   = start + cnt[row];
    float a0 = 0.f, a1 = 0.f, a2 = 0.f, a3 = 0.f;
    int j = start;
    for (; j + 4 <= end; j += 4) {
        int2 e0 = cv[j + 0];
        int2 e1 = cv[j + 1];
        int2 e2 = cv[j + 2];
        int2 e3 = cv[j + 3];
        ushort4 p0 = *(const ushort4*)(pre + (size_t)e0.x * D_OUT + lane * 4);
        ushort4 p1 = *(const ushort4*)(pre + (size_t)e1.x * D_OUT + lane * 4);
        ushort4 p2 = *(const ushort4*)(pre + (size_t)e2.x * D_OUT + lane * 4);
        ushort4 p3 = *(const ushort4*)(pre + (size_t)e3.x * D_OUT + lane * 4);
        float w0 = __int_as_float(e0.y), w1 = __int_as_float(e1.y);
        float w2 = __int_as_float(e2.y), w3 = __int_as_float(e3.y);
        a0 += w0 * bf2f(p0.x) + w1 * bf2f(p1.x) + w2 * bf2f(p2.x) + w3 * bf2f(p3.x);
        a1 += w0 * bf2f(p0.y) + w1 * bf2f(p1.y) + w2 * bf2f(p2.y) + w3 * bf2f(p3.y);
        a2 += w0 * bf2f(p0.z) + w1 * bf2f(p1.z) + w2 * bf2f(p2.z) + w3 * bf2f(p3.z);
        a3 += w0 * bf2f(p0.w) + w1 * bf2f(p1.w) + w2 * bf2f(p2.w) + w3 * bf2f(p3.w);
    }
    for (; j < end; ++j) {
        int2 e = cv[j];
        float w = __int_as_float(e.y);
        ushort4 p = *(const ushort4*)(pre + (size_t)e.x * D_OUT + lane * 4);
        a0 += w * bf2f(p.x);
        a1 += w * bf2f(p.y);
        a2 += w * bf2f(p.z);
        a3 += w * bf2f(p.w);
    }
    float4 o = make_float4(fmaxf(a0, 0.f), fmaxf(a1, 0.f), fmaxf(a2, 0.f), fmaxf(a3, 0.f));
    *(float4*)(out + (size_t)row * D_OUT + lane * 4) = o;
}

extern "C" void kernel_launch(void* const* d_in, const int* in_sizes, int n_in,
                              void* d_out, int out_size, void* d_ws, size_t ws_size,
                              hipStream_t stream) {
    const float* x    = (const float*)d_in[0];
    const float* W    = (const float*)d_in[1];
    const int*   rows = (const int*)d_in[2];
    const int*   cols = (const int*)d_in[3];
    const float* vals = (const float*)d_in[4];
    const float* cw   = (const float*)d_in[5];
    float* out = (float*)d_out;

    char* ws = (char*)d_ws;
    size_t off = 0;
    auto alloc = [&](size_t bytes) -> void* {
        void* p = ws + off;
        off += (bytes + 255) & ~(size_t)255;
        return p;
    };
    unsigned short* pre  = (unsigned short*)alloc((size_t)SUP * N_NODES * D_OUT * 2); // 76.8 MB
    unsigned short* Wt   = (unsigned short*)alloc((size_t)SUP * D_OUT * D_IN * 2);    // 0.8 MB
    int* base            = (int*)alloc((size_t)N_NODES * 4);
    int* cnt             = (int*)alloc((size_t)N_NODES * 4);
    int* bucket_cursor   = (int*)alloc((size_t)NBUCK * 4);
    int2* cv             = (int2*)alloc((size_t)NBUCK * CAP * 8);                     // 20.9 MB
    // buck aliases the pre region (dead before gemm writes pre; stream-ordered)
    int2* buck           = (int2*)pre;

    hipMemsetAsync(bucket_cursor, 0, (size_t)NBUCK * 4, stream);

    bucket_kernel<<<(TOT_E + CHUNK - 1) / CHUNK, 256, 0, stream>>>(rows, cols, vals, cw,
                                                                   bucket_cursor, buck);
    sort_kernel<<<NBUCK, 256, 0, stream>>>(buck, bucket_cursor, cv, base, cnt);
    wprep_kernel<<<(SUP * D_IN * D_OUT + 255) / 256, 256, 0, stream>>>(W, Wt);
    gemm_kernel<<<dim3((N_NODES + 127) / 128, D_OUT / 128, SUP), 256, 0, stream>>>(x, Wt, pre);
    spmm_kernel<<<N_NODES / 4, 256, 0, stream>>>(pre, base, cnt, cv, out);
}